// Round 9
// baseline (281.570 us; speedup 1.0000x reference)
//
#include <hip/hip_runtime.h>
#include <math.h>

#define NROWS 16384
#define NR2 32768  // audio ++ video
#define DIM 256
#define MC 1024
#define GBM 128
#define NCHUNK 16  // 8 col-blocks x 2 wave-cols

constexpr float kDecay = 0.99f;
constexpr float kEps = 1e-5f;
constexpr float kTemp = 0.1f;
constexpr float kCommit = 0.25f;
constexpr float kMaxEnt = 6.93147180559945f; // ln(1024)

using short8 = __attribute__((ext_vector_type(8))) short;
using f32x4 = __attribute__((ext_vector_type(4))) float;

__device__ __forceinline__ float wave_sum(float v) {
#pragma unroll
  for (int off = 32; off > 0; off >>= 1) v += __shfl_xor(v, off);
  return v;
}

__device__ __forceinline__ unsigned short f2bf(float f) {
  union { float f; unsigned int u; } c;
  c.f = f;
  const unsigned int u = c.u;
  return (unsigned short)((u + 0x7FFFu + ((u >> 16) & 1u)) >> 16);  // RNE
}
__device__ __forceinline__ float bf2f(unsigned short h) {
  union { unsigned int u; float f; } c;
  c.u = ((unsigned int)h) << 16;
  return c.f;
}

// fused: bf16 copy + row sum-of-squares for audio++video++embedding.
__global__ __launch_bounds__(256) void convert_all(const float* __restrict__ A,
                                                   const float* __restrict__ V,
                                                   const float* __restrict__ E,
                                                   unsigned short* __restrict__ av_bf,
                                                   unsigned short* __restrict__ e_bf,
                                                   float* __restrict__ xsq,
                                                   float* __restrict__ esq) {
  const int row = (int)((blockIdx.x * blockDim.x + threadIdx.x) >> 6);
  const int lane = threadIdx.x & 63;
  const float* src;
  unsigned short* dst;
  float* sqo;
  if (row < NR2) {
    src = (row < NROWS) ? (A + (size_t)row * DIM) : (V + (size_t)(row - NROWS) * DIM);
    dst = av_bf + (size_t)row * DIM;
    sqo = xsq + row;
  } else {
    const int r = row - NR2;
    src = E + (size_t)r * DIM;
    dst = e_bf + (size_t)r * DIM;
    sqo = esq + r;
  }
  const float4 x = *reinterpret_cast<const float4*>(src + (lane << 2));
  float s = x.x * x.x + x.y * x.y + x.z * x.z + x.w * x.w;
  ushort4 b;
  b.x = f2bf(x.x); b.y = f2bf(x.y); b.z = f2bf(x.z); b.w = f2bf(x.w);
  *reinterpret_cast<ushort4*>(dst + (lane << 2)) = b;
  s = wave_sum(s);
  if (lane == 0) *sqo = s;
}

// ---- LDS-free flat GEMM: 128x128 tile, 4 independent waves (2x2), each wave
// 64x64 via 4x4 frags of 16x16x32 MFMA, fragments loaded DIRECTLY from global
// (dwordx4/lane, K fully unrolled -> compiler pipelines). NO __syncthreads.
// Epilogue: per-wave LDS slab [64 cols][36] f32; lane-serial row scans,
// no max subtraction (raw exp sums fp32-safe: s in [-23,0], logits in [-10,10]).

// dist pass: GEMM + fused per-chunk raw partials {se, ws, bestv, besti}
__global__ __launch_bounds__(256, 2) void gemm_dist(const unsigned short* __restrict__ X,
                                                    const unsigned short* __restrict__ W,
                                                    const float* __restrict__ xsq,
                                                    const float* __restrict__ esq,
                                                    float4* __restrict__ pd4) {
  __shared__ __align__(16) float slab_all[4 * 2304];  // 9216B per wave
  const int tid = threadIdx.x;
  const int l = tid & 63;
  const int w = tid >> 6;
  const int wr = w >> 1, wc = w & 1;
  int bid = blockIdx.y * 8 + blockIdx.x;
  bid = (bid & 7) * 256 + (bid >> 3);  // XCD-aware bijective swizzle (2048 % 8 == 0)
  const int bx = bid & 7;
  const int by = bid >> 3;
  const int row0 = by * GBM;
  const int col0 = bx * GBM;
  const int l15 = l & 15, lg = l >> 4;
  const unsigned short* abase[4];
  const unsigned short* bbase[4];
#pragma unroll
  for (int m = 0; m < 4; ++m)
    abase[m] = X + (size_t)(row0 + wr * 64 + m * 16 + l15) * DIM + lg * 8;
#pragma unroll
  for (int n = 0; n < 4; ++n)
    bbase[n] = W + (size_t)(col0 + wc * 64 + n * 16 + l15) * DIM + lg * 8;
  f32x4 acc[4][4] = {};
#pragma unroll
  for (int t = 0; t < 4; ++t) {
    short8 af[4][2], bq[4][2];
#pragma unroll
    for (int m = 0; m < 4; ++m)
#pragma unroll
      for (int ks = 0; ks < 2; ++ks)
        af[m][ks] = *reinterpret_cast<const short8*>(abase[m] + t * 64 + ks * 32);
#pragma unroll
    for (int n = 0; n < 4; ++n)
#pragma unroll
      for (int ks = 0; ks < 2; ++ks)
        bq[n][ks] = *reinterpret_cast<const short8*>(bbase[n] + t * 64 + ks * 32);
#pragma unroll
    for (int ks = 0; ks < 2; ++ks)
#pragma unroll
      for (int m = 0; m < 4; ++m)
#pragma unroll
        for (int n = 0; n < 4; ++n)
          acc[m][n] =
              __builtin_amdgcn_mfma_f32_16x16x32_bf16(af[m][ks], bq[n][ks], acc[m][n], 0, 0, 0);
  }
  // epilogue: dump to per-wave slab, lane-serial one-pass scan (no max needed)
  float* slab = slab_all + w * 2304;
  const int r = l & 31, h = l >> 5;
  const int chunk = bx * 2 + wc;
#pragma unroll
  for (int ph = 0; ph < 2; ++ph) {
#pragma unroll
    for (int mm = 0; mm < 2; ++mm)
#pragma unroll
      for (int n = 0; n < 4; ++n)
        *reinterpret_cast<f32x4*>(slab + (n * 16 + l15) * 36 + mm * 16 + lg * 4) =
            acc[ph * 2 + mm][n];
    const int grow = row0 + wr * 64 + ph * 32 + r;
    const float xs = xsq[grow];
    float se = 0.f, wsum = 0.f, bv = INFINITY;
    int bi = 0;
#pragma unroll
    for (int c = 0; c < 32; ++c) {
      const int colg = col0 + wc * 64 + h * 32 + c;
      const float dist = esq[colg] + xs - 2.0f * slab[(h * 32 + c) * 36 + r];
      if (dist < bv) { bv = dist; bi = colg; }
      const float sneg = -sqrtf(fmaxf(dist, 0.0f));
      const float e = __expf(sneg);  // s in [-23,0]: raw exp safe
      se += e;
      wsum += e * sneg;
    }
    const float ose = __shfl_xor(se, 32);
    const float ows = __shfl_xor(wsum, 32);
    const float obv = __shfl_xor(bv, 32);
    const int obi = __shfl_xor(bi, 32);
    se += ose;
    wsum += ows;
    if (obv < bv || (obv == bv && obi < bi)) { bv = obv; bi = obi; }
    if (h == 0)
      pd4[(size_t)chunk * NR2 + grow] = make_float4(se, wsum, bv, __int_as_float(bi));
  }
}

// merge 16 chunk partials per row: plain sums + argmin; emit idx, adj
__global__ __launch_bounds__(256) void dist_combine(const float4* __restrict__ pd4,
                                                    int* __restrict__ idx_out,
                                                    float* __restrict__ adj_out) {
  const int row = blockIdx.x * 256 + threadIdx.x;
  float SE = 0.f, WS = 0.f, BV = INFINITY;
  int BI = 0;
#pragma unroll
  for (int c = 0; c < NCHUNK; ++c) {
    const float4 st = pd4[(size_t)c * NR2 + row];
    SE += st.x;
    WS += st.y;
    if (st.z < BV) { BV = st.z; BI = __float_as_int(st.w); }
  }
  const float H = logf(SE) - WS / SE - 1e-5f * (float)MC;
  idx_out[row] = BI;
  adj_out[row] = 1.0f - H / kMaxEnt;
}

// EMA scatter from bf16 copies: one block per original row pair
__global__ __launch_bounds__(256) void scatter_ema(const unsigned short* __restrict__ av,
                                                   const int* __restrict__ idx,
                                                   const float* __restrict__ adj,
                                                   float* __restrict__ acc_a,
                                                   float* __restrict__ acc_v,
                                                   float* __restrict__ cnt_a,
                                                   float* __restrict__ cnt_v) {
  const int row = blockIdx.x;
  const int d = threadIdx.x;
  const float s = bf2f(av[(size_t)row * DIM + d]) + bf2f(av[(size_t)(row + NROWS) * DIM + d]);
  const int ia = idx[row], iv = idx[row + NROWS];
  const float wa = adj[row], wv = adj[row + NROWS];
  atomicAdd(acc_a + (size_t)ia * DIM + d, wa * s);
  atomicAdd(acc_v + (size_t)iv * DIM + d, wv * s);
  if (d == 0) {
    atomicAdd(cnt_a + ia, wa);
    atomicAdd(cnt_v + iv, wv);
  }
}

// two-pass EMA count update with Laplace smoothing; single block of 1024
__global__ __launch_bounds__(1024) void ec_kernel(const float* __restrict__ ema_count,
                                                  const float* __restrict__ cnt_v,
                                                  const float* __restrict__ cnt_a,
                                                  float* __restrict__ ec_out) {
  __shared__ float red[1024];
  const int m = threadIdx.x;
  float ec = kDecay * ema_count[m] + (1.f - kDecay) * cnt_v[m];
  red[m] = ec;
  __syncthreads();
  for (int s = 512; s > 0; s >>= 1) {
    if (m < s) red[m] += red[m + s];
    __syncthreads();
  }
  float n = red[0];
  __syncthreads();
  ec = (ec + kEps) / (n + MC * kEps) * n;
  ec = kDecay * ec + (1.f - kDecay) * cnt_a[m];
  red[m] = ec;
  __syncthreads();
  for (int s = 512; s > 0; s >>= 1) {
    if (m < s) red[m] += red[m + s];
    __syncthreads();
  }
  n = red[0];
  ec = (ec + kEps) / (n + MC * kEps) * n;
  ec_out[m] = ec;
}

// emb_new = ew2/ec; en = row-normalized, emitted as bf16. one block per code
__global__ __launch_bounds__(256) void en_kernel(const float* __restrict__ ema_weight,
                                                 const float* __restrict__ acc_v,
                                                 const float* __restrict__ acc_a,
                                                 const float* __restrict__ ec,
                                                 unsigned short* __restrict__ en_b) {
  const int mcode = blockIdx.x;
  const int d = threadIdx.x;
  const size_t o = (size_t)mcode * DIM + d;
  float ew = kDecay * ema_weight[o] + 0.5f * (1.f - kDecay) * acc_v[o];
  ew = kDecay * ew + 0.5f * (1.f - kDecay) * acc_a[o];
  const float e = ew / ec[mcode];
  __shared__ float red[256];
  red[d] = e * e;
  __syncthreads();
  for (int s = 128; s > 0; s >>= 1) {
    if (d < s) red[d] += red[d + s];
    __syncthreads();
  }
  const float nrm = sqrtf(red[0]);
  en_b[o] = f2bf(e / fmaxf(nrm, 1e-8f));
}

// NCE pass: flat GEMM + fused per-chunk raw exp-sum (logits in [-10,10]: safe)
__global__ __launch_bounds__(256, 2) void gemm_nce(const unsigned short* __restrict__ X,
                                                   const unsigned short* __restrict__ W,
                                                   const float* __restrict__ xsq,
                                                   float* __restrict__ pn) {
  __shared__ __align__(16) float slab_all[4 * 2304];
  const int tid = threadIdx.x;
  const int l = tid & 63;
  const int w = tid >> 6;
  const int wr = w >> 1, wc = w & 1;
  int bid = blockIdx.y * 8 + blockIdx.x;
  bid = (bid & 7) * 256 + (bid >> 3);
  const int bx = bid & 7;
  const int by = bid >> 3;
  const int row0 = by * GBM;
  const int col0 = bx * GBM;
  const int l15 = l & 15, lg = l >> 4;
  const unsigned short* abase[4];
  const unsigned short* bbase[4];
#pragma unroll
  for (int m = 0; m < 4; ++m)
    abase[m] = X + (size_t)(row0 + wr * 64 + m * 16 + l15) * DIM + lg * 8;
#pragma unroll
  for (int n = 0; n < 4; ++n)
    bbase[n] = W + (size_t)(col0 + wc * 64 + n * 16 + l15) * DIM + lg * 8;
  f32x4 acc[4][4] = {};
#pragma unroll
  for (int t = 0; t < 4; ++t) {
    short8 af[4][2], bq[4][2];
#pragma unroll
    for (int m = 0; m < 4; ++m)
#pragma unroll
      for (int ks = 0; ks < 2; ++ks)
        af[m][ks] = *reinterpret_cast<const short8*>(abase[m] + t * 64 + ks * 32);
#pragma unroll
    for (int n = 0; n < 4; ++n)
#pragma unroll
      for (int ks = 0; ks < 2; ++ks)
        bq[n][ks] = *reinterpret_cast<const short8*>(bbase[n] + t * 64 + ks * 32);
#pragma unroll
    for (int ks = 0; ks < 2; ++ks)
#pragma unroll
      for (int m = 0; m < 4; ++m)
#pragma unroll
        for (int n = 0; n < 4; ++n)
          acc[m][n] =
              __builtin_amdgcn_mfma_f32_16x16x32_bf16(af[m][ks], bq[n][ks], acc[m][n], 0, 0, 0);
  }
  float* slab = slab_all + w * 2304;
  const int r = l & 31, h = l >> 5;
  const int chunk = bx * 2 + wc;
#pragma unroll
  for (int ph = 0; ph < 2; ++ph) {
#pragma unroll
    for (int mm = 0; mm < 2; ++mm)
#pragma unroll
      for (int n = 0; n < 4; ++n)
        *reinterpret_cast<f32x4*>(slab + (n * 16 + l15) * 36 + mm * 16 + lg * 4) =
            acc[ph * 2 + mm][n];
    const int grow = row0 + wr * 64 + ph * 32 + r;
    const float inv = 1.0f / (fmaxf(sqrtf(xsq[grow]), 1e-8f) * kTemp);
    float se = 0.f;
#pragma unroll
    for (int c = 0; c < 32; ++c) se += __expf(slab[(h * 32 + c) * 36 + r] * inv);
    se += __shfl_xor(se, 32);
    if (h == 0) pn[(size_t)chunk * NR2 + grow] = se;
  }
}

// merge raw exp-sums + gather self/coupled logits via recomputed dots; block partials
__global__ __launch_bounds__(256) void nce_combine(const float* __restrict__ pn,
                                                   const unsigned short* __restrict__ av_bf,
                                                   const unsigned short* __restrict__ en_bf,
                                                   const float* __restrict__ xsq,
                                                   const int* __restrict__ idx,
                                                   float* __restrict__ part) {
  __shared__ float sp[8];
  const int row = (int)((blockIdx.x * blockDim.x + threadIdx.x) >> 6);
  const int lane = threadIdx.x & 63;
  const int wib = threadIdx.x >> 6;
  const float m = (lane < NCHUNK) ? pn[(size_t)lane * NR2 + row] : 0.f;
  const float SE = wave_sum(m);
  const float lse = logf(SE);
  const int si = idx[row], ci = idx[row ^ NROWS];
  const ushort4 x4 = *reinterpret_cast<const ushort4*>(av_bf + (size_t)row * DIM + (lane << 2));
  const ushort4 s4 = *reinterpret_cast<const ushort4*>(en_bf + (size_t)si * DIM + (lane << 2));
  const ushort4 c4 = *reinterpret_cast<const ushort4*>(en_bf + (size_t)ci * DIM + (lane << 2));
  float ds = bf2f(x4.x) * bf2f(s4.x) + bf2f(x4.y) * bf2f(s4.y) + bf2f(x4.z) * bf2f(s4.z) +
             bf2f(x4.w) * bf2f(s4.w);
  float dc = bf2f(x4.x) * bf2f(c4.x) + bf2f(x4.y) * bf2f(c4.y) + bf2f(x4.z) * bf2f(c4.z) +
             bf2f(x4.w) * bf2f(c4.w);
  ds = wave_sum(ds);
  dc = wave_sum(dc);
  const float inv = 1.0f / (fmaxf(sqrtf(xsq[row]), 1e-8f) * kTemp);
  if (lane == 0) {
    sp[wib] = ds * inv - lse;
    sp[4 + wib] = dc * inv - lse;
  }
  __syncthreads();
  if (threadIdx.x == 0) {
    part[blockIdx.x] = sp[0] + sp[1] + sp[2] + sp[3];
    part[8192 + blockIdx.x] = sp[4] + sp[5] + sp[6] + sp[7];
  }
}

// reduce 2x8192 partials -> scalar loss. 1 block x 1024.
__global__ __launch_bounds__(1024) void finalize(const float* __restrict__ part,
                                                 float* __restrict__ out) {
  const int tid = threadIdx.x;
  const int lane = tid & 63;
  const int wid = tid >> 6;
  float ss = 0.f, sc = 0.f;
  for (int i = tid; i < 8192; i += 1024) {
    ss += part[i];
    sc += part[8192 + i];
  }
  ss = wave_sum(ss);
  sc = wave_sum(sc);
  __shared__ float red[16][2];
  if (lane == 0) { red[wid][0] = ss; red[wid][1] = sc; }
  __syncthreads();
  if (tid == 0) {
    float t0 = 0.f, t1 = 0.f;
#pragma unroll
    for (int i = 0; i < 16; ++i) { t0 += red[i][0]; t1 += red[i][1]; }
    out[0] = -(kCommit / (32.0f * (float)NROWS)) * (kCommit * t0 + (1.f - kCommit) * t1);
  }
}

extern "C" void kernel_launch(void* const* d_in, const int* in_sizes, int n_in, void* d_out,
                              int out_size, void* d_ws, size_t ws_size, hipStream_t stream) {
  const float* audio = (const float*)d_in[0];
  const float* video = (const float*)d_in[1];
  const float* emb = (const float*)d_in[2];
  const float* ema_count = (const float*)d_in[3];
  const float* ema_weight = (const float*)d_in[4];
  float* out = (float*)d_out;

  float* ws = (float*)d_ws;
  size_t off = 0;
  float4* pd4 = (float4*)(ws + off); off += (size_t)NCHUNK * NR2 * 4;  // 8 MB
  float* pn = ws + off; off += (size_t)NCHUNK * NR2;                   // 2 MB
  float* esq = ws + off; off += MC;
  float* xsq = ws + off; off += NR2;
  float* adj = ws + off; off += NR2;
  int* idx = (int*)(ws + off); off += NR2;
  float* cnt_a = ws + off; off += MC;
  float* cnt_v = ws + off; off += MC;
  float* acc_a = ws + off; off += (size_t)MC * DIM;
  float* acc_v = ws + off; off += (size_t)MC * DIM;
  float* ec = ws + off; off += MC;
  float* part = ws + off; off += 16384;
  unsigned short* av_bf = (unsigned short*)(ws + off); off += (size_t)NR2 * DIM / 2;
  unsigned short* e_bf = (unsigned short*)(ws + off); off += (size_t)MC * DIM / 2;
  unsigned short* en_bf = (unsigned short*)(ws + off); off += (size_t)MC * DIM / 2;

  hipMemsetAsync(cnt_a, 0, (size_t)(2 * MC + 2 * (size_t)MC * DIM) * sizeof(float), stream);

  const dim3 b256(256);
  const dim3 ggrid(MC / GBM, NR2 / GBM);  // (8, 256)

  convert_all<<<(NR2 + MC) / 4, b256, 0, stream>>>(audio, video, emb, av_bf, e_bf, xsq, esq);

  gemm_dist<<<ggrid, b256, 0, stream>>>(av_bf, e_bf, xsq, esq, pd4);
  dist_combine<<<NR2 / 256, b256, 0, stream>>>(pd4, idx, adj);

  scatter_ema<<<NROWS, b256, 0, stream>>>(av_bf, idx, adj, acc_a, acc_v, cnt_a, cnt_v);
  ec_kernel<<<1, 1024, 0, stream>>>(ema_count, cnt_v, cnt_a, ec);
  en_kernel<<<MC, b256, 0, stream>>>(ema_weight, acc_v, acc_a, ec, en_bf);

  gemm_nce<<<ggrid, b256, 0, stream>>>(av_bf, en_bf, xsq, pn);
  nce_combine<<<NR2 / 4, b256, 0, stream>>>(pn, av_bf, en_bf, xsq, idx, part);

  finalize<<<1, 1024, 0, stream>>>(part, out);
}

// Round 10
// 233.882 us; speedup vs baseline: 1.2039x; 1.2039x over previous
//
#include <hip/hip_runtime.h>
#include <math.h>

#define NROWS 16384
#define NR2 32768  // audio ++ video
#define DIM 256
#define MC 1024
#define GBM 128
#define GBK 64
#define NCHUNK 16  // 8 col-blocks x 2 wave-cols

constexpr float kDecay = 0.99f;
constexpr float kEps = 1e-5f;
constexpr float kTemp = 0.1f;
constexpr float kCommit = 0.25f;
constexpr float kMaxEnt = 6.93147180559945f; // ln(1024)

using short8 = __attribute__((ext_vector_type(8))) short;
using f32x4 = __attribute__((ext_vector_type(4))) float;

__device__ __forceinline__ float wave_sum(float v) {
#pragma unroll
  for (int off = 32; off > 0; off >>= 1) v += __shfl_xor(v, off);
  return v;
}

__device__ __forceinline__ unsigned short f2bf(float f) {
  union { float f; unsigned int u; } c;
  c.f = f;
  const unsigned int u = c.u;
  return (unsigned short)((u + 0x7FFFu + ((u >> 16) & 1u)) >> 16);  // RNE
}
__device__ __forceinline__ float bf2f(unsigned short h) {
  union { unsigned int u; float f; } c;
  c.u = ((unsigned int)h) << 16;
  return c.f;
}

// fused: bf16 copy + row sum-of-squares for audio++video++embedding.
__global__ __launch_bounds__(256) void convert_all(const float* __restrict__ A,
                                                   const float* __restrict__ V,
                                                   const float* __restrict__ E,
                                                   unsigned short* __restrict__ av_bf,
                                                   unsigned short* __restrict__ e_bf,
                                                   float* __restrict__ xsq,
                                                   float* __restrict__ esq) {
  const int row = (int)((blockIdx.x * blockDim.x + threadIdx.x) >> 6);
  const int lane = threadIdx.x & 63;
  const float* src;
  unsigned short* dst;
  float* sqo;
  if (row < NR2) {
    src = (row < NROWS) ? (A + (size_t)row * DIM) : (V + (size_t)(row - NROWS) * DIM);
    dst = av_bf + (size_t)row * DIM;
    sqo = xsq + row;
  } else {
    const int r = row - NR2;
    src = E + (size_t)r * DIM;
    dst = e_bf + (size_t)r * DIM;
    sqo = esq + r;
  }
  const float4 x = *reinterpret_cast<const float4*>(src + (lane << 2));
  float s = x.x * x.x + x.y * x.y + x.z * x.z + x.w * x.w;
  ushort4 b;
  b.x = f2bf(x.x); b.y = f2bf(x.y); b.z = f2bf(x.z); b.w = f2bf(x.w);
  *reinterpret_cast<ushort4*>(dst + (lane << 2)) = b;
  s = wave_sum(s);
  if (lane == 0) *sqo = s;
}

// ---- GEMM: 128x128 tile, BK=64, 4 waves (2x2), single-buffer LDS staging via
// global_load_lds with XOR swizzle ((row&7)<<4) on both source and read side.
// MFMA operands SWAPPED (acc = mfma(B,A)) so each lane holds whole output-ROW
// slices -> column reduction is in-register; 2 shfl_xor rounds finish it.
// acc[m][n][reg]: Xrow = row0+wr*64+m*16+(l&15), code = col0+wc*64+n*16+(l>>4)*4+reg
__device__ __forceinline__ void stage_tile(const unsigned short* __restrict__ X,
                                           const unsigned short* __restrict__ W,
                                           char* lds, int k0, int row0, int col0, int w, int l) {
#pragma unroll
  for (int j = 0; j < 4; ++j) {
    const int sbase = __builtin_amdgcn_readfirstlane((w * 4 + j) * 1024);
    const int s = sbase + (l << 4);
    const int row = s >> 7;
    const int colb = s & 127;
    const int scolb = colb ^ ((row & 7) << 4);
    const char* srcA = (const char*)(X + (size_t)(row0 + row) * DIM + k0) + scolb;
    const char* srcB = (const char*)(W + (size_t)(col0 + row) * DIM + k0) + scolb;
    __builtin_amdgcn_global_load_lds(
        (const __attribute__((address_space(1))) unsigned int*)srcA,
        (__attribute__((address_space(3))) unsigned int*)(lds + sbase), 16, 0, 0);
    __builtin_amdgcn_global_load_lds(
        (const __attribute__((address_space(1))) unsigned int*)srcB,
        (__attribute__((address_space(3))) unsigned int*)(lds + 16384 + sbase), 16, 0, 0);
  }
}

__device__ __forceinline__ void mfma_step(const char* lds, f32x4 acc[4][4], int wr, int wc,
                                          int l) {
#pragma unroll
  for (int ks = 0; ks < 2; ++ks) {
    short8 af[4], bq[4];
    const int cb = ks * 64 + (l >> 4) * 16;
#pragma unroll
    for (int m = 0; m < 4; ++m) {
      const int ar = wr * 64 + m * 16 + (l & 15);
      af[m] = *reinterpret_cast<const short8*>(lds + ar * 128 + (cb ^ ((ar & 7) << 4)));
    }
#pragma unroll
    for (int n = 0; n < 4; ++n) {
      const int br = wc * 64 + n * 16 + (l & 15);
      bq[n] = *reinterpret_cast<const short8*>(lds + 16384 + br * 128 + (cb ^ ((br & 7) << 4)));
    }
#pragma unroll
    for (int m = 0; m < 4; ++m)
#pragma unroll
      for (int n = 0; n < 4; ++n)  // SWAPPED: D^T -> rows in lanes
        acc[m][n] = __builtin_amdgcn_mfma_f32_16x16x32_bf16(bq[n], af[m], acc[m][n], 0, 0, 0);
  }
}

// dist pass: GEMM + fused per-chunk raw partials {se, ws, bestv, besti}
__global__ __launch_bounds__(256, 4) void gemm_dist(const unsigned short* __restrict__ X,
                                                    const unsigned short* __restrict__ W,
                                                    const float* __restrict__ xsq,
                                                    const float* __restrict__ esq,
                                                    float4* __restrict__ pd4) {
  __shared__ __align__(16) char lds[32768];
  const int tid = threadIdx.x;
  const int l = tid & 63;
  const int w = tid >> 6;
  const int wr = w >> 1, wc = w & 1;
  int bid = blockIdx.y * 8 + blockIdx.x;
  bid = (bid & 7) * 256 + (bid >> 3);  // XCD-aware bijective swizzle (2048 % 8 == 0)
  const int bx = bid & 7;
  const int by = bid >> 3;
  const int row0 = by * GBM;
  const int col0 = bx * GBM;
  f32x4 acc[4][4] = {};
#pragma unroll
  for (int t = 0; t < 4; ++t) {
    stage_tile(X, W, lds, t * GBK, row0, col0, w, l);
    __syncthreads();
    mfma_step(lds, acc, wr, wc, l);
    __syncthreads();
  }
  // epilogue: in-register column scan per output row; 2 shfl rounds to merge lg groups
  const int l15 = l & 15, lg = l >> 4;
  const int chunk = bx * 2 + wc;
  float xsv[4], es[4][4];
#pragma unroll
  for (int m = 0; m < 4; ++m) xsv[m] = xsq[row0 + wr * 64 + m * 16 + l15];
#pragma unroll
  for (int n = 0; n < 4; ++n)
#pragma unroll
    for (int reg = 0; reg < 4; ++reg)
      es[n][reg] = esq[col0 + wc * 64 + n * 16 + lg * 4 + reg];
#pragma unroll
  for (int m = 0; m < 4; ++m) {
    float se = 0.f, wsabs = 0.f, bv = INFINITY;
    int bi = 0;
#pragma unroll
    for (int n = 0; n < 4; ++n)
#pragma unroll
      for (int reg = 0; reg < 4; ++reg) {
        const float dist = fmaf(-2.0f, acc[m][n][reg], xsv[m]) + es[n][reg];
        const int colg = col0 + wc * 64 + n * 16 + lg * 4 + reg;
        if (dist < bv) { bv = dist; bi = colg; }
        const float sabs = sqrtf(fmaxf(dist, 0.0f));
        const float e = __expf(-sabs);  // s in [-23,0]: raw exp safe
        se += e;
        wsabs = fmaf(e, sabs, wsabs);
      }
#pragma unroll
    for (int off = 16; off <= 32; off <<= 1) {
      se += __shfl_xor(se, off);
      wsabs += __shfl_xor(wsabs, off);
      const float obv = __shfl_xor(bv, off);
      const int obi = __shfl_xor(bi, off);
      if (obv < bv || (obv == bv && obi < bi)) { bv = obv; bi = obi; }
    }
    if (lg == 0) {
      const int grow = row0 + wr * 64 + m * 16 + l15;
      pd4[(size_t)chunk * NR2 + grow] = make_float4(se, -wsabs, bv, __int_as_float(bi));
    }
  }
}

// merge 16 chunk partials per row: plain sums + argmin; emit idx, adj
__global__ __launch_bounds__(256) void dist_combine(const float4* __restrict__ pd4,
                                                    int* __restrict__ idx_out,
                                                    float* __restrict__ adj_out) {
  const int row = blockIdx.x * 256 + threadIdx.x;
  float SE = 0.f, WS = 0.f, BV = INFINITY;
  int BI = 0;
#pragma unroll
  for (int c = 0; c < NCHUNK; ++c) {
    const float4 st = pd4[(size_t)c * NR2 + row];
    SE += st.x;
    WS += st.y;
    if (st.z < BV) { BV = st.z; BI = __float_as_int(st.w); }
  }
  const float H = logf(SE) - WS / SE - 1e-5f * (float)MC;
  idx_out[row] = BI;
  adj_out[row] = 1.0f - H / kMaxEnt;
}

// EMA scatter from bf16 copies: one block per original row pair
__global__ __launch_bounds__(256) void scatter_ema(const unsigned short* __restrict__ av,
                                                   const int* __restrict__ idx,
                                                   const float* __restrict__ adj,
                                                   float* __restrict__ acc_a,
                                                   float* __restrict__ acc_v,
                                                   float* __restrict__ cnt_a,
                                                   float* __restrict__ cnt_v) {
  const int row = blockIdx.x;
  const int d = threadIdx.x;
  const float s = bf2f(av[(size_t)row * DIM + d]) + bf2f(av[(size_t)(row + NROWS) * DIM + d]);
  const int ia = idx[row], iv = idx[row + NROWS];
  const float wa = adj[row], wv = adj[row + NROWS];
  atomicAdd(acc_a + (size_t)ia * DIM + d, wa * s);
  atomicAdd(acc_v + (size_t)iv * DIM + d, wv * s);
  if (d == 0) {
    atomicAdd(cnt_a + ia, wa);
    atomicAdd(cnt_v + iv, wv);
  }
}

// two-pass EMA count update with Laplace smoothing; single block of 1024
__global__ __launch_bounds__(1024) void ec_kernel(const float* __restrict__ ema_count,
                                                  const float* __restrict__ cnt_v,
                                                  const float* __restrict__ cnt_a,
                                                  float* __restrict__ ec_out) {
  __shared__ float red[1024];
  const int m = threadIdx.x;
  float ec = kDecay * ema_count[m] + (1.f - kDecay) * cnt_v[m];
  red[m] = ec;
  __syncthreads();
  for (int s = 512; s > 0; s >>= 1) {
    if (m < s) red[m] += red[m + s];
    __syncthreads();
  }
  float n = red[0];
  __syncthreads();
  ec = (ec + kEps) / (n + MC * kEps) * n;
  ec = kDecay * ec + (1.f - kDecay) * cnt_a[m];
  red[m] = ec;
  __syncthreads();
  for (int s = 512; s > 0; s >>= 1) {
    if (m < s) red[m] += red[m + s];
    __syncthreads();
  }
  n = red[0];
  ec = (ec + kEps) / (n + MC * kEps) * n;
  ec_out[m] = ec;
}

// emb_new = ew2/ec; en = row-normalized, emitted as bf16. one block per code
__global__ __launch_bounds__(256) void en_kernel(const float* __restrict__ ema_weight,
                                                 const float* __restrict__ acc_v,
                                                 const float* __restrict__ acc_a,
                                                 const float* __restrict__ ec,
                                                 unsigned short* __restrict__ en_b) {
  const int mcode = blockIdx.x;
  const int d = threadIdx.x;
  const size_t o = (size_t)mcode * DIM + d;
  float ew = kDecay * ema_weight[o] + 0.5f * (1.f - kDecay) * acc_v[o];
  ew = kDecay * ew + 0.5f * (1.f - kDecay) * acc_a[o];
  const float e = ew / ec[mcode];
  __shared__ float red[256];
  red[d] = e * e;
  __syncthreads();
  for (int s = 128; s > 0; s >>= 1) {
    if (d < s) red[d] += red[d + s];
    __syncthreads();
  }
  const float nrm = sqrtf(red[0]);
  en_b[o] = f2bf(e / fmaxf(nrm, 1e-8f));
}

// NCE pass: GEMM + fused per-chunk raw exp-sum (logits in [-10,10]: safe)
__global__ __launch_bounds__(256, 4) void gemm_nce(const unsigned short* __restrict__ X,
                                                   const unsigned short* __restrict__ W,
                                                   const float* __restrict__ xsq,
                                                   float* __restrict__ pn) {
  __shared__ __align__(16) char lds[32768];
  const int tid = threadIdx.x;
  const int l = tid & 63;
  const int w = tid >> 6;
  const int wr = w >> 1, wc = w & 1;
  int bid = blockIdx.y * 8 + blockIdx.x;
  bid = (bid & 7) * 256 + (bid >> 3);
  const int bx = bid & 7;
  const int by = bid >> 3;
  const int row0 = by * GBM;
  const int col0 = bx * GBM;
  f32x4 acc[4][4] = {};
#pragma unroll
  for (int t = 0; t < 4; ++t) {
    stage_tile(X, W, lds, t * GBK, row0, col0, w, l);
    __syncthreads();
    mfma_step(lds, acc, wr, wc, l);
    __syncthreads();
  }
  const int l15 = l & 15, lg = l >> 4;
  const int chunk = bx * 2 + wc;
#pragma unroll
  for (int m = 0; m < 4; ++m) {
    const int grow = row0 + wr * 64 + m * 16 + l15;
    const float inv = 1.0f / (fmaxf(sqrtf(xsq[grow]), 1e-8f) * kTemp);
    float se = 0.f;
#pragma unroll
    for (int n = 0; n < 4; ++n)
#pragma unroll
      for (int reg = 0; reg < 4; ++reg) se += __expf(acc[m][n][reg] * inv);
    se += __shfl_xor(se, 16);
    se += __shfl_xor(se, 32);
    if (lg == 0) pn[(size_t)chunk * NR2 + grow] = se;
  }
}

// merge raw exp-sums + gather self/coupled logits via recomputed dots; block partials
__global__ __launch_bounds__(256) void nce_combine(const float* __restrict__ pn,
                                                   const unsigned short* __restrict__ av_bf,
                                                   const unsigned short* __restrict__ en_bf,
                                                   const float* __restrict__ xsq,
                                                   const int* __restrict__ idx,
                                                   float* __restrict__ part) {
  __shared__ float sp[8];
  const int row = (int)((blockIdx.x * blockDim.x + threadIdx.x) >> 6);
  const int lane = threadIdx.x & 63;
  const int wib = threadIdx.x >> 6;
  const float m = (lane < NCHUNK) ? pn[(size_t)lane * NR2 + row] : 0.f;
  const float SE = wave_sum(m);
  const float lse = logf(SE);
  const int si = idx[row], ci = idx[row ^ NROWS];
  const ushort4 x4 = *reinterpret_cast<const ushort4*>(av_bf + (size_t)row * DIM + (lane << 2));
  const ushort4 s4 = *reinterpret_cast<const ushort4*>(en_bf + (size_t)si * DIM + (lane << 2));
  const ushort4 c4 = *reinterpret_cast<const ushort4*>(en_bf + (size_t)ci * DIM + (lane << 2));
  float ds = bf2f(x4.x) * bf2f(s4.x) + bf2f(x4.y) * bf2f(s4.y) + bf2f(x4.z) * bf2f(s4.z) +
             bf2f(x4.w) * bf2f(s4.w);
  float dc = bf2f(x4.x) * bf2f(c4.x) + bf2f(x4.y) * bf2f(c4.y) + bf2f(x4.z) * bf2f(c4.z) +
             bf2f(x4.w) * bf2f(c4.w);
  ds = wave_sum(ds);
  dc = wave_sum(dc);
  const float inv = 1.0f / (fmaxf(sqrtf(xsq[row]), 1e-8f) * kTemp);
  if (lane == 0) {
    sp[wib] = ds * inv - lse;
    sp[4 + wib] = dc * inv - lse;
  }
  __syncthreads();
  if (threadIdx.x == 0) {
    part[blockIdx.x] = sp[0] + sp[1] + sp[2] + sp[3];
    part[8192 + blockIdx.x] = sp[4] + sp[5] + sp[6] + sp[7];
  }
}

// reduce 2x8192 partials -> scalar loss. 1 block x 1024.
__global__ __launch_bounds__(1024) void finalize(const float* __restrict__ part,
                                                 float* __restrict__ out) {
  const int tid = threadIdx.x;
  const int lane = tid & 63;
  const int wid = tid >> 6;
  float ss = 0.f, sc = 0.f;
  for (int i = tid; i < 8192; i += 1024) {
    ss += part[i];
    sc += part[8192 + i];
  }
  ss = wave_sum(ss);
  sc = wave_sum(sc);
  __shared__ float red[16][2];
  if (lane == 0) { red[wid][0] = ss; red[wid][1] = sc; }
  __syncthreads();
  if (tid == 0) {
    float t0 = 0.f, t1 = 0.f;
#pragma unroll
    for (int i = 0; i < 16; ++i) { t0 += red[i][0]; t1 += red[i][1]; }
    out[0] = -(kCommit / (32.0f * (float)NROWS)) * (kCommit * t0 + (1.f - kCommit) * t1);
  }
}

extern "C" void kernel_launch(void* const* d_in, const int* in_sizes, int n_in, void* d_out,
                              int out_size, void* d_ws, size_t ws_size, hipStream_t stream) {
  const float* audio = (const float*)d_in[0];
  const float* video = (const float*)d_in[1];
  const float* emb = (const float*)d_in[2];
  const float* ema_count = (const float*)d_in[3];
  const float* ema_weight = (const float*)d_in[4];
  float* out = (float*)d_out;

  float* ws = (float*)d_ws;
  size_t off = 0;
  float4* pd4 = (float4*)(ws + off); off += (size_t)NCHUNK * NR2 * 4;  // 8 MB
  float* pn = ws + off; off += (size_t)NCHUNK * NR2;                   // 2 MB
  float* esq = ws + off; off += MC;
  float* xsq = ws + off; off += NR2;
  float* adj = ws + off; off += NR2;
  int* idx = (int*)(ws + off); off += NR2;
  float* cnt_a = ws + off; off += MC;
  float* cnt_v = ws + off; off += MC;
  float* acc_a = ws + off; off += (size_t)MC * DIM;
  float* acc_v = ws + off; off += (size_t)MC * DIM;
  float* ec = ws + off; off += MC;
  float* part = ws + off; off += 16384;
  unsigned short* av_bf = (unsigned short*)(ws + off); off += (size_t)NR2 * DIM / 2;
  unsigned short* e_bf = (unsigned short*)(ws + off); off += (size_t)MC * DIM / 2;
  unsigned short* en_bf = (unsigned short*)(ws + off); off += (size_t)MC * DIM / 2;

  hipMemsetAsync(cnt_a, 0, (size_t)(2 * MC + 2 * (size_t)MC * DIM) * sizeof(float), stream);

  const dim3 b256(256);
  const dim3 ggrid(MC / GBM, NR2 / GBM);  // (8, 256)

  convert_all<<<(NR2 + MC) / 4, b256, 0, stream>>>(audio, video, emb, av_bf, e_bf, xsq, esq);

  gemm_dist<<<ggrid, b256, 0, stream>>>(av_bf, e_bf, xsq, esq, pd4);
  dist_combine<<<NR2 / 256, b256, 0, stream>>>(pd4, idx, adj);

  scatter_ema<<<NROWS, b256, 0, stream>>>(av_bf, idx, adj, acc_a, acc_v, cnt_a, cnt_v);
  ec_kernel<<<1, 1024, 0, stream>>>(ema_count, cnt_v, cnt_a, ec);
  en_kernel<<<MC, b256, 0, stream>>>(ema_weight, acc_v, acc_a, ec, en_bf);

  gemm_nce<<<ggrid, b256, 0, stream>>>(av_bf, en_bf, xsq, pn);
  nce_combine<<<NR2 / 4, b256, 0, stream>>>(pn, av_bf, en_bf, xsq, idx, part);

  finalize<<<1, 1024, 0, stream>>>(part, out);
}

// Round 11
// 209.909 us; speedup vs baseline: 1.3414x; 1.1142x over previous
//
#include <hip/hip_runtime.h>
#include <math.h>

#define NROWS 16384
#define NR2 32768  // audio ++ video
#define DIM 256
#define MC 1024
#define GBM 128
#define GBK 64
#define NCHUNK 16  // 8 col-blocks x 2 wave-cols

constexpr float kDecay = 0.99f;
constexpr float kEps = 1e-5f;
constexpr float kTemp = 0.1f;
constexpr float kCommit = 0.25f;
constexpr float kMaxEnt = 6.93147180559945f; // ln(1024)

using short8 = __attribute__((ext_vector_type(8))) short;
using f32x4 = __attribute__((ext_vector_type(4))) float;

__device__ __forceinline__ float wave_sum(float v) {
#pragma unroll
  for (int off = 32; off > 0; off >>= 1) v += __shfl_xor(v, off);
  return v;
}

__device__ __forceinline__ unsigned short f2bf(float f) {
  union { float f; unsigned int u; } c;
  c.f = f;
  const unsigned int u = c.u;
  return (unsigned short)((u + 0x7FFFu + ((u >> 16) & 1u)) >> 16);  // RNE
}
__device__ __forceinline__ float bf2f(unsigned short h) {
  union { unsigned int u; float f; } c;
  c.u = ((unsigned int)h) << 16;
  return c.f;
}

// fused: bf16 copy + row sum-of-squares for audio++video++embedding.
__global__ __launch_bounds__(256) void convert_all(const float* __restrict__ A,
                                                   const float* __restrict__ V,
                                                   const float* __restrict__ E,
                                                   unsigned short* __restrict__ av_bf,
                                                   unsigned short* __restrict__ e_bf,
                                                   float* __restrict__ xsq,
                                                   float* __restrict__ esq) {
  const int row = (int)((blockIdx.x * blockDim.x + threadIdx.x) >> 6);
  const int lane = threadIdx.x & 63;
  const float* src;
  unsigned short* dst;
  float* sqo;
  if (row < NR2) {
    src = (row < NROWS) ? (A + (size_t)row * DIM) : (V + (size_t)(row - NROWS) * DIM);
    dst = av_bf + (size_t)row * DIM;
    sqo = xsq + row;
  } else {
    const int r = row - NR2;
    src = E + (size_t)r * DIM;
    dst = e_bf + (size_t)r * DIM;
    sqo = esq + r;
  }
  const float4 x = *reinterpret_cast<const float4*>(src + (lane << 2));
  float s = x.x * x.x + x.y * x.y + x.z * x.z + x.w * x.w;
  ushort4 b;
  b.x = f2bf(x.x); b.y = f2bf(x.y); b.z = f2bf(x.z); b.w = f2bf(x.w);
  *reinterpret_cast<ushort4*>(dst + (lane << 2)) = b;
  s = wave_sum(s);
  if (lane == 0) *sqo = s;
}

// ---- GEMM: 128x128 tile, BK=64, 4 waves (2x2), single-buffer LDS staging via
// global_load_lds with XOR swizzle ((row&7)<<4) on both source and read side.
// MFMA operands SWAPPED (acc = mfma(B,A)): lane holds output-ROW slices, column
// reduction is in-register + 2 shfl rounds. Epilogue constants (esq/xsq slices)
// are STREAMED FROM LDS (stashed at kernel start) to keep VGPR+AGPR under the
// 128/lane budget at 4 blocks/CU -- preloading them in regs caused 50MB spills.
__device__ __forceinline__ void stage_tile(const unsigned short* __restrict__ X,
                                           const unsigned short* __restrict__ W,
                                           char* lds, int k0, int row0, int col0, int w, int l) {
#pragma unroll
  for (int j = 0; j < 4; ++j) {
    const int sbase = __builtin_amdgcn_readfirstlane((w * 4 + j) * 1024);
    const int s = sbase + (l << 4);
    const int row = s >> 7;
    const int colb = s & 127;
    const int scolb = colb ^ ((row & 7) << 4);
    const char* srcA = (const char*)(X + (size_t)(row0 + row) * DIM + k0) + scolb;
    const char* srcB = (const char*)(W + (size_t)(col0 + row) * DIM + k0) + scolb;
    __builtin_amdgcn_global_load_lds(
        (const __attribute__((address_space(1))) unsigned int*)srcA,
        (__attribute__((address_space(3))) unsigned int*)(lds + sbase), 16, 0, 0);
    __builtin_amdgcn_global_load_lds(
        (const __attribute__((address_space(1))) unsigned int*)srcB,
        (__attribute__((address_space(3))) unsigned int*)(lds + 16384 + sbase), 16, 0, 0);
  }
}

__device__ __forceinline__ void mfma_step(const char* lds, f32x4 acc[4][4], int wr, int wc,
                                          int l) {
#pragma unroll
  for (int ks = 0; ks < 2; ++ks) {
    short8 af[4], bq[4];
    const int cb = ks * 64 + (l >> 4) * 16;
#pragma unroll
    for (int m = 0; m < 4; ++m) {
      const int ar = wr * 64 + m * 16 + (l & 15);
      af[m] = *reinterpret_cast<const short8*>(lds + ar * 128 + (cb ^ ((ar & 7) << 4)));
    }
#pragma unroll
    for (int n = 0; n < 4; ++n) {
      const int br = wc * 64 + n * 16 + (l & 15);
      bq[n] = *reinterpret_cast<const short8*>(lds + 16384 + br * 128 + (cb ^ ((br & 7) << 4)));
    }
#pragma unroll
    for (int m = 0; m < 4; ++m)
#pragma unroll
      for (int n = 0; n < 4; ++n)  // SWAPPED: D^T -> rows in lanes
        acc[m][n] = __builtin_amdgcn_mfma_f32_16x16x32_bf16(bq[n], af[m], acc[m][n], 0, 0, 0);
  }
}

// dist pass: GEMM + fused per-chunk raw partials {se, ws, bestv, besti}
__global__ __launch_bounds__(256, 4) void gemm_dist(const unsigned short* __restrict__ X,
                                                    const unsigned short* __restrict__ W,
                                                    const float* __restrict__ xsq,
                                                    const float* __restrict__ esq,
                                                    float4* __restrict__ pd4) {
  __shared__ __align__(16) char lds[32768 + 1024];
  float* esq_s = (float*)(lds + 32768);       // [128] codebook col slice
  float* xsq_s = (float*)(lds + 32768 + 512); // [128] X row slice
  const int tid = threadIdx.x;
  const int l = tid & 63;
  const int w = tid >> 6;
  const int wr = w >> 1, wc = w & 1;
  int bid = blockIdx.y * 8 + blockIdx.x;
  bid = (bid & 7) * 256 + (bid >> 3);  // XCD-aware bijective swizzle (2048 % 8 == 0)
  const int bx = bid & 7;
  const int by = bid >> 3;
  const int row0 = by * GBM;
  const int col0 = bx * GBM;
  // stash epilogue constants (covered by the K-loop's first barrier)
  if (tid < 128) esq_s[tid] = esq[col0 + tid];
  else xsq_s[tid - 128] = xsq[row0 + tid - 128];
  f32x4 acc[4][4] = {};
#pragma unroll
  for (int t = 0; t < 4; ++t) {
    stage_tile(X, W, lds, t * GBK, row0, col0, w, l);
    __syncthreads();
    mfma_step(lds, acc, wr, wc, l);
    if (t < 3) __syncthreads();
  }
  // epilogue: in-register column scan per output row; constants streamed from LDS
  const int l15 = l & 15, lg = l >> 4;
  const int chunk = bx * 2 + wc;
#pragma unroll
  for (int m = 0; m < 4; ++m) {
    const float xs = xsq_s[wr * 64 + m * 16 + l15];
    float se = 0.f, wsabs = 0.f, bv = INFINITY;
    int bi = 0;
#pragma unroll
    for (int n = 0; n < 4; ++n) {
      const f32x4 es4 = *reinterpret_cast<const f32x4*>(&esq_s[wc * 64 + n * 16 + lg * 4]);
#pragma unroll
      for (int reg = 0; reg < 4; ++reg) {
        const float dist = fmaf(-2.0f, acc[m][n][reg], xs) + es4[reg];
        const int colg = col0 + wc * 64 + n * 16 + lg * 4 + reg;
        if (dist < bv) { bv = dist; bi = colg; }
        const float sabs = sqrtf(fmaxf(dist, 0.0f));
        const float e = __expf(-sabs);  // s in [-23,0]: raw exp safe
        se += e;
        wsabs = fmaf(e, sabs, wsabs);
      }
    }
#pragma unroll
    for (int off = 16; off <= 32; off <<= 1) {
      se += __shfl_xor(se, off);
      wsabs += __shfl_xor(wsabs, off);
      const float obv = __shfl_xor(bv, off);
      const int obi = __shfl_xor(bi, off);
      if (obv < bv || (obv == bv && obi < bi)) { bv = obv; bi = obi; }
    }
    if (lg == 0) {
      const int grow = row0 + wr * 64 + m * 16 + l15;
      pd4[(size_t)chunk * NR2 + grow] = make_float4(se, -wsabs, bv, __int_as_float(bi));
    }
  }
}

// merge 16 chunk partials per row: plain sums + argmin; emit idx, adj
__global__ __launch_bounds__(256) void dist_combine(const float4* __restrict__ pd4,
                                                    int* __restrict__ idx_out,
                                                    float* __restrict__ adj_out) {
  const int row = blockIdx.x * 256 + threadIdx.x;
  float SE = 0.f, WS = 0.f, BV = INFINITY;
  int BI = 0;
#pragma unroll
  for (int c = 0; c < NCHUNK; ++c) {
    const float4 st = pd4[(size_t)c * NR2 + row];
    SE += st.x;
    WS += st.y;
    if (st.z < BV) { BV = st.z; BI = __float_as_int(st.w); }
  }
  const float H = logf(SE) - WS / SE - 1e-5f * (float)MC;
  idx_out[row] = BI;
  adj_out[row] = 1.0f - H / kMaxEnt;
}

// EMA scatter from bf16 copies: one block per original row pair
__global__ __launch_bounds__(256) void scatter_ema(const unsigned short* __restrict__ av,
                                                   const int* __restrict__ idx,
                                                   const float* __restrict__ adj,
                                                   float* __restrict__ acc_a,
                                                   float* __restrict__ acc_v,
                                                   float* __restrict__ cnt_a,
                                                   float* __restrict__ cnt_v) {
  const int row = blockIdx.x;
  const int d = threadIdx.x;
  const float s = bf2f(av[(size_t)row * DIM + d]) + bf2f(av[(size_t)(row + NROWS) * DIM + d]);
  const int ia = idx[row], iv = idx[row + NROWS];
  const float wa = adj[row], wv = adj[row + NROWS];
  atomicAdd(acc_a + (size_t)ia * DIM + d, wa * s);
  atomicAdd(acc_v + (size_t)iv * DIM + d, wv * s);
  if (d == 0) {
    atomicAdd(cnt_a + ia, wa);
    atomicAdd(cnt_v + iv, wv);
  }
}

// two-pass EMA count update with Laplace smoothing; single block of 1024
__global__ __launch_bounds__(1024) void ec_kernel(const float* __restrict__ ema_count,
                                                  const float* __restrict__ cnt_v,
                                                  const float* __restrict__ cnt_a,
                                                  float* __restrict__ ec_out) {
  __shared__ float red[1024];
  const int m = threadIdx.x;
  float ec = kDecay * ema_count[m] + (1.f - kDecay) * cnt_v[m];
  red[m] = ec;
  __syncthreads();
  for (int s = 512; s > 0; s >>= 1) {
    if (m < s) red[m] += red[m + s];
    __syncthreads();
  }
  float n = red[0];
  __syncthreads();
  ec = (ec + kEps) / (n + MC * kEps) * n;
  ec = kDecay * ec + (1.f - kDecay) * cnt_a[m];
  red[m] = ec;
  __syncthreads();
  for (int s = 512; s > 0; s >>= 1) {
    if (m < s) red[m] += red[m + s];
    __syncthreads();
  }
  n = red[0];
  ec = (ec + kEps) / (n + MC * kEps) * n;
  ec_out[m] = ec;
}

// emb_new = ew2/ec; en = row-normalized, emitted as bf16. one block per code
__global__ __launch_bounds__(256) void en_kernel(const float* __restrict__ ema_weight,
                                                 const float* __restrict__ acc_v,
                                                 const float* __restrict__ acc_a,
                                                 const float* __restrict__ ec,
                                                 unsigned short* __restrict__ en_b) {
  const int mcode = blockIdx.x;
  const int d = threadIdx.x;
  const size_t o = (size_t)mcode * DIM + d;
  float ew = kDecay * ema_weight[o] + 0.5f * (1.f - kDecay) * acc_v[o];
  ew = kDecay * ew + 0.5f * (1.f - kDecay) * acc_a[o];
  const float e = ew / ec[mcode];
  __shared__ float red[256];
  red[d] = e * e;
  __syncthreads();
  for (int s = 128; s > 0; s >>= 1) {
    if (d < s) red[d] += red[d + s];
    __syncthreads();
  }
  const float nrm = sqrtf(red[0]);
  en_b[o] = f2bf(e / fmaxf(nrm, 1e-8f));
}

// NCE pass: GEMM + fused per-chunk raw exp-sum (logits in [-10,10]: safe)
__global__ __launch_bounds__(256, 4) void gemm_nce(const unsigned short* __restrict__ X,
                                                   const unsigned short* __restrict__ W,
                                                   const float* __restrict__ xsq,
                                                   float* __restrict__ pn) {
  __shared__ __align__(16) char lds[32768 + 512];
  float* xsq_s = (float*)(lds + 32768);  // [128] X row slice
  const int tid = threadIdx.x;
  const int l = tid & 63;
  const int w = tid >> 6;
  const int wr = w >> 1, wc = w & 1;
  int bid = blockIdx.y * 8 + blockIdx.x;
  bid = (bid & 7) * 256 + (bid >> 3);
  const int bx = bid & 7;
  const int by = bid >> 3;
  const int row0 = by * GBM;
  const int col0 = bx * GBM;
  if (tid < 128) xsq_s[tid] = xsq[row0 + tid];
  f32x4 acc[4][4] = {};
#pragma unroll
  for (int t = 0; t < 4; ++t) {
    stage_tile(X, W, lds, t * GBK, row0, col0, w, l);
    __syncthreads();
    mfma_step(lds, acc, wr, wc, l);
    if (t < 3) __syncthreads();
  }
  const int l15 = l & 15, lg = l >> 4;
  const int chunk = bx * 2 + wc;
#pragma unroll
  for (int m = 0; m < 4; ++m) {
    const float xs = xsq_s[wr * 64 + m * 16 + l15];
    const float inv = 10.0f * rsqrtf(fmaxf(xs, 1e-16f));  // 1/(sqrt(xs)*0.1)
    float se = 0.f;
#pragma unroll
    for (int n = 0; n < 4; ++n)
#pragma unroll
      for (int reg = 0; reg < 4; ++reg) se += __expf(acc[m][n][reg] * inv);
    se += __shfl_xor(se, 16);
    se += __shfl_xor(se, 32);
    if (lg == 0) pn[(size_t)chunk * NR2 + (row0 + wr * 64 + m * 16 + l15)] = se;
  }
}

// merge raw exp-sums + gather self/coupled logits via recomputed dots; block partials
__global__ __launch_bounds__(256) void nce_combine(const float* __restrict__ pn,
                                                   const unsigned short* __restrict__ av_bf,
                                                   const unsigned short* __restrict__ en_bf,
                                                   const float* __restrict__ xsq,
                                                   const int* __restrict__ idx,
                                                   float* __restrict__ part) {
  __shared__ float sp[8];
  const int row = (int)((blockIdx.x * blockDim.x + threadIdx.x) >> 6);
  const int lane = threadIdx.x & 63;
  const int wib = threadIdx.x >> 6;
  const float m = (lane < NCHUNK) ? pn[(size_t)lane * NR2 + row] : 0.f;
  const float SE = wave_sum(m);
  const float lse = logf(SE);
  const int si = idx[row], ci = idx[row ^ NROWS];
  const ushort4 x4 = *reinterpret_cast<const ushort4*>(av_bf + (size_t)row * DIM + (lane << 2));
  const ushort4 s4 = *reinterpret_cast<const ushort4*>(en_bf + (size_t)si * DIM + (lane << 2));
  const ushort4 c4 = *reinterpret_cast<const ushort4*>(en_bf + (size_t)ci * DIM + (lane << 2));
  float ds = bf2f(x4.x) * bf2f(s4.x) + bf2f(x4.y) * bf2f(s4.y) + bf2f(x4.z) * bf2f(s4.z) +
             bf2f(x4.w) * bf2f(s4.w);
  float dc = bf2f(x4.x) * bf2f(c4.x) + bf2f(x4.y) * bf2f(c4.y) + bf2f(x4.z) * bf2f(c4.z) +
             bf2f(x4.w) * bf2f(c4.w);
  ds = wave_sum(ds);
  dc = wave_sum(dc);
  const float inv = 1.0f / (fmaxf(sqrtf(xsq[row]), 1e-8f) * kTemp);
  if (lane == 0) {
    sp[wib] = ds * inv - lse;
    sp[4 + wib] = dc * inv - lse;
  }
  __syncthreads();
  if (threadIdx.x == 0) {
    part[blockIdx.x] = sp[0] + sp[1] + sp[2] + sp[3];
    part[8192 + blockIdx.x] = sp[4] + sp[5] + sp[6] + sp[7];
  }
}

// reduce 2x8192 partials -> scalar loss. 1 block x 1024.
__global__ __launch_bounds__(1024) void finalize(const float* __restrict__ part,
                                                 float* __restrict__ out) {
  const int tid = threadIdx.x;
  const int lane = tid & 63;
  const int wid = tid >> 6;
  float ss = 0.f, sc = 0.f;
  for (int i = tid; i < 8192; i += 1024) {
    ss += part[i];
    sc += part[8192 + i];
  }
  ss = wave_sum(ss);
  sc = wave_sum(sc);
  __shared__ float red[16][2];
  if (lane == 0) { red[wid][0] = ss; red[wid][1] = sc; }
  __syncthreads();
  if (tid == 0) {
    float t0 = 0.f, t1 = 0.f;
#pragma unroll
    for (int i = 0; i < 16; ++i) { t0 += red[i][0]; t1 += red[i][1]; }
    out[0] = -(kCommit / (32.0f * (float)NROWS)) * (kCommit * t0 + (1.f - kCommit) * t1);
  }
}

extern "C" void kernel_launch(void* const* d_in, const int* in_sizes, int n_in, void* d_out,
                              int out_size, void* d_ws, size_t ws_size, hipStream_t stream) {
  const float* audio = (const float*)d_in[0];
  const float* video = (const float*)d_in[1];
  const float* emb = (const float*)d_in[2];
  const float* ema_count = (const float*)d_in[3];
  const float* ema_weight = (const float*)d_in[4];
  float* out = (float*)d_out;

  float* ws = (float*)d_ws;
  size_t off = 0;
  float4* pd4 = (float4*)(ws + off); off += (size_t)NCHUNK * NR2 * 4;  // 8 MB
  float* pn = ws + off; off += (size_t)NCHUNK * NR2;                   // 2 MB
  float* esq = ws + off; off += MC;
  float* xsq = ws + off; off += NR2;
  float* adj = ws + off; off += NR2;
  int* idx = (int*)(ws + off); off += NR2;
  float* cnt_a = ws + off; off += MC;
  float* cnt_v = ws + off; off += MC;
  float* acc_a = ws + off; off += (size_t)MC * DIM;
  float* acc_v = ws + off; off += (size_t)MC * DIM;
  float* ec = ws + off; off += MC;
  float* part = ws + off; off += 16384;
  unsigned short* av_bf = (unsigned short*)(ws + off); off += (size_t)NR2 * DIM / 2;
  unsigned short* e_bf = (unsigned short*)(ws + off); off += (size_t)MC * DIM / 2;
  unsigned short* en_bf = (unsigned short*)(ws + off); off += (size_t)MC * DIM / 2;

  hipMemsetAsync(cnt_a, 0, (size_t)(2 * MC + 2 * (size_t)MC * DIM) * sizeof(float), stream);

  const dim3 b256(256);
  const dim3 ggrid(MC / GBM, NR2 / GBM);  // (8, 256)

  convert_all<<<(NR2 + MC) / 4, b256, 0, stream>>>(audio, video, emb, av_bf, e_bf, xsq, esq);

  gemm_dist<<<ggrid, b256, 0, stream>>>(av_bf, e_bf, xsq, esq, pd4);
  dist_combine<<<NR2 / 256, b256, 0, stream>>>(pd4, idx, adj);

  scatter_ema<<<NROWS, b256, 0, stream>>>(av_bf, idx, adj, acc_a, acc_v, cnt_a, cnt_v);
  ec_kernel<<<1, 1024, 0, stream>>>(ema_count, cnt_v, cnt_a, ec);
  en_kernel<<<MC, b256, 0, stream>>>(ema_weight, acc_v, acc_a, ec, en_bf);

  gemm_nce<<<ggrid, b256, 0, stream>>>(av_bf, en_bf, xsq, pn);
  nce_combine<<<NR2 / 4, b256, 0, stream>>>(pn, av_bf, en_bf, xsq, idx, part);

  finalize<<<1, 1024, 0, stream>>>(part, out);
}

// Round 13
// 201.421 us; speedup vs baseline: 1.3979x; 1.0421x over previous
//
#include <hip/hip_runtime.h>
#include <math.h>

#define NROWS 16384
#define NR2 32768  // audio ++ video
#define DIM 256
#define MC 1024
#define GBM 128
#define GBK 64
#define NCHUNK 16  // 8 col-blocks x 2 wave-cols

constexpr float kDecay = 0.99f;
constexpr float kEps = 1e-5f;
constexpr float kTemp = 0.1f;
constexpr float kCommit = 0.25f;
constexpr float kMaxEnt = 6.93147180559945f; // ln(1024)

using short8 = __attribute__((ext_vector_type(8))) short;
using f32x4 = __attribute__((ext_vector_type(4))) float;

__device__ __forceinline__ float wave_sum(float v) {
#pragma unroll
  for (int off = 32; off > 0; off >>= 1) v += __shfl_xor(v, off);
  return v;
}

__device__ __forceinline__ unsigned short f2bf(float f) {
  union { float f; unsigned int u; } c;
  c.f = f;
  const unsigned int u = c.u;
  return (unsigned short)((u + 0x7FFFu + ((u >> 16) & 1u)) >> 16);  // RNE
}
__device__ __forceinline__ float bf2f(unsigned short h) {
  union { unsigned int u; float f; } c;
  c.u = ((unsigned int)h) << 16;
  return c.f;
}

// fused: bf16 copy + row sum-of-squares for audio++video++embedding.
__global__ __launch_bounds__(256) void convert_all(const float* __restrict__ A,
                                                   const float* __restrict__ V,
                                                   const float* __restrict__ E,
                                                   unsigned short* __restrict__ av_bf,
                                                   unsigned short* __restrict__ e_bf,
                                                   float* __restrict__ xsq,
                                                   float* __restrict__ esq) {
  const int row = (int)((blockIdx.x * blockDim.x + threadIdx.x) >> 6);
  const int lane = threadIdx.x & 63;
  const float* src;
  unsigned short* dst;
  float* sqo;
  if (row < NR2) {
    src = (row < NROWS) ? (A + (size_t)row * DIM) : (V + (size_t)(row - NROWS) * DIM);
    dst = av_bf + (size_t)row * DIM;
    sqo = xsq + row;
  } else {
    const int r = row - NR2;
    src = E + (size_t)r * DIM;
    dst = e_bf + (size_t)r * DIM;
    sqo = esq + r;
  }
  const float4 x = *reinterpret_cast<const float4*>(src + (lane << 2));
  float s = x.x * x.x + x.y * x.y + x.z * x.z + x.w * x.w;
  ushort4 b;
  b.x = f2bf(x.x); b.y = f2bf(x.y); b.z = f2bf(x.z); b.w = f2bf(x.w);
  *reinterpret_cast<ushort4*>(dst + (lane << 2)) = b;
  s = wave_sum(s);
  if (lane == 0) *sqo = s;
}

// ---- GEMM: 128x128 tile, BK=64, 4 waves (2x2), single-buffer LDS staging via
// global_load_lds with XOR swizzle ((row&7)<<4) on both source and read side.
// MFMA operands SWAPPED (acc = mfma(B,A)): lane holds output-ROW slices; column
// reduction is in-register + 2 shfl rounds. Epilogue constants streamed from LDS.
__device__ __forceinline__ void stage_tile(const unsigned short* __restrict__ X,
                                           const unsigned short* __restrict__ W,
                                           char* lds, int k0, int row0, int col0, int w, int l) {
#pragma unroll
  for (int j = 0; j < 4; ++j) {
    const int sbase = __builtin_amdgcn_readfirstlane((w * 4 + j) * 1024);
    const int s = sbase + (l << 4);
    const int row = s >> 7;
    const int colb = s & 127;
    const int scolb = colb ^ ((row & 7) << 4);
    const char* srcA = (const char*)(X + (size_t)(row0 + row) * DIM + k0) + scolb;
    const char* srcB = (const char*)(W + (size_t)(col0 + row) * DIM + k0) + scolb;
    __builtin_amdgcn_global_load_lds(
        (const __attribute__((address_space(1))) unsigned int*)srcA,
        (__attribute__((address_space(3))) unsigned int*)(lds + sbase), 16, 0, 0);
    __builtin_amdgcn_global_load_lds(
        (const __attribute__((address_space(1))) unsigned int*)srcB,
        (__attribute__((address_space(3))) unsigned int*)(lds + 16384 + sbase), 16, 0, 0);
  }
}

__device__ __forceinline__ void mfma_step(const char* lds, f32x4 acc[4][4], int wr, int wc,
                                          int l) {
#pragma unroll
  for (int ks = 0; ks < 2; ++ks) {
    short8 af[4], bq[4];
    const int cb = ks * 64 + (l >> 4) * 16;
#pragma unroll
    for (int m = 0; m < 4; ++m) {
      const int ar = wr * 64 + m * 16 + (l & 15);
      af[m] = *reinterpret_cast<const short8*>(lds + ar * 128 + (cb ^ ((ar & 7) << 4)));
    }
#pragma unroll
    for (int n = 0; n < 4; ++n) {
      const int br = wc * 64 + n * 16 + (l & 15);
      bq[n] = *reinterpret_cast<const short8*>(lds + 16384 + br * 128 + (cb ^ ((br & 7) << 4)));
    }
#pragma unroll
    for (int m = 0; m < 4; ++m)
#pragma unroll
      for (int n = 0; n < 4; ++n)  // SWAPPED: D^T -> rows in lanes
        acc[m][n] = __builtin_amdgcn_mfma_f32_16x16x32_bf16(bq[n], af[m], acc[m][n], 0, 0, 0);
  }
}

// dist pass: GEMM + fused per-chunk raw partials {se, ws, bestv, besti}
__global__ __launch_bounds__(256, 4) void gemm_dist(const unsigned short* __restrict__ X,
                                                    const unsigned short* __restrict__ W,
                                                    const float* __restrict__ xsq,
                                                    const float* __restrict__ esq,
                                                    float4* __restrict__ pd4) {
  __shared__ __align__(16) char lds[32768 + 1024];
  float* esq_s = (float*)(lds + 32768);       // [128] codebook col slice
  float* xsq_s = (float*)(lds + 32768 + 512); // [128] X row slice
  const int tid = threadIdx.x;
  const int l = tid & 63;
  const int w = tid >> 6;
  const int wr = w >> 1, wc = w & 1;
  int bid = blockIdx.y * 8 + blockIdx.x;
  bid = (bid & 7) * 256 + (bid >> 3);  // XCD-aware bijective swizzle (2048 % 8 == 0)
  const int bx = bid & 7;
  const int by = bid >> 3;
  const int row0 = by * GBM;
  const int col0 = bx * GBM;
  if (tid < 128) esq_s[tid] = esq[col0 + tid];
  else xsq_s[tid - 128] = xsq[row0 + tid - 128];
  f32x4 acc[4][4] = {};
#pragma unroll
  for (int t = 0; t < 4; ++t) {
    stage_tile(X, W, lds, t * GBK, row0, col0, w, l);
    __syncthreads();
    mfma_step(lds, acc, wr, wc, l);
    if (t < 3) __syncthreads();
  }
  const int l15 = l & 15, lg = l >> 4;
  const int chunk = bx * 2 + wc;
#pragma unroll
  for (int m = 0; m < 4; ++m) {
    const float xs = xsq_s[wr * 64 + m * 16 + l15];
    float se = 0.f, wsabs = 0.f, bv = INFINITY;
    int bi = 0;
#pragma unroll
    for (int n = 0; n < 4; ++n) {
      const f32x4 es4 = *reinterpret_cast<const f32x4*>(&esq_s[wc * 64 + n * 16 + lg * 4]);
#pragma unroll
      for (int reg = 0; reg < 4; ++reg) {
        const float dist = fmaf(-2.0f, acc[m][n][reg], xs) + es4[reg];
        const int colg = col0 + wc * 64 + n * 16 + lg * 4 + reg;
        if (dist < bv) { bv = dist; bi = colg; }
        const float sabs = sqrtf(fmaxf(dist, 0.0f));
        const float e = __expf(-sabs);  // s in [-23,0]: raw exp safe
        se += e;
        wsabs = fmaf(e, sabs, wsabs);
      }
    }
#pragma unroll
    for (int off = 16; off <= 32; off <<= 1) {
      se += __shfl_xor(se, off);
      wsabs += __shfl_xor(wsabs, off);
      const float obv = __shfl_xor(bv, off);
      const int obi = __shfl_xor(bi, off);
      if (obv < bv || (obv == bv && obi < bi)) { bv = obv; bi = obi; }
    }
    if (lg == 0) {
      const int grow = row0 + wr * 64 + m * 16 + l15;
      pd4[(size_t)chunk * NR2 + grow] = make_float4(se, -wsabs, bv, __int_as_float(bi));
    }
  }
}

// merged combine+scatter: one block per row pair (r, r+NROWS).
// lanes 0-15 merge chunks for r, 16-31 for r2; then all 256 threads scatter.
__global__ __launch_bounds__(256) void combine_scatter(
    const float4* __restrict__ pd4, const unsigned short* __restrict__ av,
    int* __restrict__ idx_out, float* __restrict__ acc_a, float* __restrict__ acc_v,
    float* __restrict__ cnt_a, float* __restrict__ cnt_v) {
  __shared__ int sidx[2];
  __shared__ float sadj[2];
  const int r = blockIdx.x;
  const int tid = threadIdx.x;
  if (tid < 32) {
    const int which = tid >> 4;             // 0: r, 1: r+NROWS
    const int c = tid & 15;
    const int row = r + which * NROWS;
    const float4 st = pd4[(size_t)c * NR2 + row];
    float SE = st.x, WS = st.y, BV = st.z;
    int BI = __float_as_int(st.w);
#pragma unroll
    for (int off = 1; off < 16; off <<= 1) {
      SE += __shfl_xor(SE, off);
      WS += __shfl_xor(WS, off);
      const float obv = __shfl_xor(BV, off);
      const int obi = __shfl_xor(BI, off);
      if (obv < BV || (obv == BV && obi < BI)) { BV = obv; BI = obi; }
    }
    if (c == 0) {
      const float H = logf(SE) - WS / SE - 1e-5f * (float)MC;
      sidx[which] = BI;
      sadj[which] = 1.0f - H / kMaxEnt;
      idx_out[row] = BI;
    }
  }
  __syncthreads();
  const int ia = sidx[0], iv = sidx[1];
  const float wa = sadj[0], wv = sadj[1];
  const int d = tid;
  const float s = bf2f(av[(size_t)r * DIM + d]) + bf2f(av[(size_t)(r + NROWS) * DIM + d]);
  atomicAdd(acc_a + (size_t)ia * DIM + d, wa * s);
  atomicAdd(acc_v + (size_t)iv * DIM + d, wv * s);
  if (d == 0) {
    atomicAdd(cnt_a + ia, wa);
    atomicAdd(cnt_v + iv, wv);
  }
}

// two-pass EMA count update with Laplace smoothing; single block of 1024
__global__ __launch_bounds__(1024) void ec_kernel(const float* __restrict__ ema_count,
                                                  const float* __restrict__ cnt_v,
                                                  const float* __restrict__ cnt_a,
                                                  float* __restrict__ ec_out) {
  __shared__ float red[1024];
  const int m = threadIdx.x;
  float ec = kDecay * ema_count[m] + (1.f - kDecay) * cnt_v[m];
  red[m] = ec;
  __syncthreads();
  for (int s = 512; s > 0; s >>= 1) {
    if (m < s) red[m] += red[m + s];
    __syncthreads();
  }
  float n = red[0];
  __syncthreads();
  ec = (ec + kEps) / (n + MC * kEps) * n;
  ec = kDecay * ec + (1.f - kDecay) * cnt_a[m];
  red[m] = ec;
  __syncthreads();
  for (int s = 512; s > 0; s >>= 1) {
    if (m < s) red[m] += red[m + s];
    __syncthreads();
  }
  n = red[0];
  ec = (ec + kEps) / (n + MC * kEps) * n;
  ec_out[m] = ec;
}

// emb_new = ew2/ec; en = row-normalized, emitted as bf16. one block per code
__global__ __launch_bounds__(256) void en_kernel(const float* __restrict__ ema_weight,
                                                 const float* __restrict__ acc_v,
                                                 const float* __restrict__ acc_a,
                                                 const float* __restrict__ ec,
                                                 unsigned short* __restrict__ en_b) {
  const int mcode = blockIdx.x;
  const int d = threadIdx.x;
  const size_t o = (size_t)mcode * DIM + d;
  float ew = kDecay * ema_weight[o] + 0.5f * (1.f - kDecay) * acc_v[o];
  ew = kDecay * ew + 0.5f * (1.f - kDecay) * acc_a[o];
  const float e = ew / ec[mcode];
  __shared__ float red[256];
  red[d] = e * e;
  __syncthreads();
  for (int s = 128; s > 0; s >>= 1) {
    if (d < s) red[d] += red[d + s];
    __syncthreads();
  }
  const float nrm = sqrtf(red[0]);
  en_b[o] = f2bf(e / fmaxf(nrm, 1e-8f));
}

// NCE pass: GEMM + per-chunk raw exp-sum + INLINE extraction of self/coupled
// logits (predicated compare against idx; static acc indexing only).
__global__ __launch_bounds__(256, 4) void gemm_nce(const unsigned short* __restrict__ X,
                                                   const unsigned short* __restrict__ W,
                                                   const float* __restrict__ xsq,
                                                   const int* __restrict__ idx,
                                                   float* __restrict__ pn,
                                                   float* __restrict__ pself,
                                                   float* __restrict__ pcoup) {
  __shared__ __align__(16) char lds[32768 + 512];
  float* xsq_s = (float*)(lds + 32768);  // [128] X row slice
  const int tid = threadIdx.x;
  const int l = tid & 63;
  const int w = tid >> 6;
  const int wr = w >> 1, wc = w & 1;
  int bid = blockIdx.y * 8 + blockIdx.x;
  bid = (bid & 7) * 256 + (bid >> 3);
  const int bx = bid & 7;
  const int by = bid >> 3;
  const int row0 = by * GBM;
  const int col0 = bx * GBM;
  if (tid < 128) xsq_s[tid] = xsq[row0 + tid];
  f32x4 acc[4][4] = {};
#pragma unroll
  for (int t = 0; t < 4; ++t) {
    stage_tile(X, W, lds, t * GBK, row0, col0, w, l);
    __syncthreads();
    mfma_step(lds, acc, wr, wc, l);
    if (t < 3) __syncthreads();
  }
  const int l15 = l & 15, lg = l >> 4;
  const int chunk = bx * 2 + wc;
  const int cbase = col0 + wc * 64 + lg * 4;
#pragma unroll
  for (int m = 0; m < 4; ++m) {
    const int grow = row0 + wr * 64 + m * 16 + l15;
    const float xs = xsq_s[wr * 64 + m * 16 + l15];
    const float inv = 10.0f * rsqrtf(fmaxf(xs, 1e-16f));  // 1/(sqrt(xs)*0.1)
    const int si = idx[grow];
    const int ci = idx[grow ^ NROWS];
    float se = 0.f;
#pragma unroll
    for (int n = 0; n < 4; ++n)
#pragma unroll
      for (int reg = 0; reg < 4; ++reg) {
        const float lv = acc[m][n][reg] * inv;
        se += __expf(lv);
        const int colg = cbase + n * 16 + reg;
        if (colg == si) pself[grow] = lv;
        if (colg == ci) pcoup[grow] = lv;
      }
    se += __shfl_xor(se, 16);
    se += __shfl_xor(se, 32);
    if (lg == 0) pn[(size_t)chunk * NR2 + grow] = se;
  }
}

// per-row: sum 16 chunk exp-sums, lse, read extracted logits; block partials
__global__ __launch_bounds__(256) void nce_reduce(const float* __restrict__ pn,
                                                  const float* __restrict__ pself,
                                                  const float* __restrict__ pcoup,
                                                  float* __restrict__ part) {
  __shared__ float sp[8];
  const int row = blockIdx.x * 256 + threadIdx.x;
  const int lane = threadIdx.x & 63;
  const int wib = threadIdx.x >> 6;
  float SE = 0.f;
#pragma unroll
  for (int c = 0; c < NCHUNK; ++c) SE += pn[(size_t)c * NR2 + row];
  const float lse = logf(SE);
  float ps = pself[row] - lse;
  float pc = pcoup[row] - lse;
  ps = wave_sum(ps);
  pc = wave_sum(pc);
  if (lane == 0) {
    sp[wib] = ps;
    sp[4 + wib] = pc;
  }
  __syncthreads();
  if (threadIdx.x == 0) {
    part[blockIdx.x] = sp[0] + sp[1] + sp[2] + sp[3];
    part[128 + blockIdx.x] = sp[4] + sp[5] + sp[6] + sp[7];
  }
}

// reduce 2x128 partials -> scalar loss. 1 block x 64.
__global__ __launch_bounds__(64) void finalize(const float* __restrict__ part,
                                               float* __restrict__ out) {
  const int l = threadIdx.x;
  float ss = part[l] + part[l + 64];
  float sc = part[128 + l] + part[192 + l];
  ss = wave_sum(ss);
  sc = wave_sum(sc);
  if (l == 0)
    out[0] = -(kCommit / (32.0f * (float)NROWS)) * (kCommit * ss + (1.f - kCommit) * sc);
}

extern "C" void kernel_launch(void* const* d_in, const int* in_sizes, int n_in, void* d_out,
                              int out_size, void* d_ws, size_t ws_size, hipStream_t stream) {
  const float* audio = (const float*)d_in[0];
  const float* video = (const float*)d_in[1];
  const float* emb = (const float*)d_in[2];
  const float* ema_count = (const float*)d_in[3];
  const float* ema_weight = (const float*)d_in[4];
  float* out = (float*)d_out;

  float* ws = (float*)d_ws;
  size_t off = 0;
  float4* pd4 = (float4*)(ws + off); off += (size_t)NCHUNK * NR2 * 4;  // 8 MB
  float* pn = ws + off; off += (size_t)NCHUNK * NR2;                   // 2 MB
  float* pself = ws + off; off += NR2;
  float* pcoup = ws + off; off += NR2;
  float* esq = ws + off; off += MC;
  float* xsq = ws + off; off += NR2;
  int* idx = (int*)(ws + off); off += NR2;
  float* cnt_a = ws + off; off += MC;
  float* cnt_v = ws + off; off += MC;
  float* acc_a = ws + off; off += (size_t)MC * DIM;
  float* acc_v = ws + off; off += (size_t)MC * DIM;
  float* ec = ws + off; off += MC;
  float* part = ws + off; off += 256;
  unsigned short* av_bf = (unsigned short*)(ws + off); off += (size_t)NR2 * DIM / 2;
  unsigned short* e_bf = (unsigned short*)(ws + off); off += (size_t)MC * DIM / 2;
  unsigned short* en_bf = (unsigned short*)(ws + off); off += (size_t)MC * DIM / 2;

  hipMemsetAsync(cnt_a, 0, (size_t)(2 * MC + 2 * (size_t)MC * DIM) * sizeof(float), stream);

  const dim3 b256(256);
  const dim3 ggrid(MC / GBM, NR2 / GBM);  // (8, 256)

  convert_all<<<(NR2 + MC) / 4, b256, 0, stream>>>(audio, video, emb, av_bf, e_bf, xsq, esq);

  gemm_dist<<<ggrid, b256, 0, stream>>>(av_bf, e_bf, xsq, esq, pd4);
  combine_scatter<<<NROWS, b256, 0, stream>>>(pd4, av_bf, idx, acc_a, acc_v, cnt_a, cnt_v);

  ec_kernel<<<1, 1024, 0, stream>>>(ema_count, cnt_v, cnt_a, ec);
  en_kernel<<<MC, b256, 0, stream>>>(ema_weight, acc_v, acc_a, ec, en_bf);

  gemm_nce<<<ggrid, b256, 0, stream>>>(av_bf, en_bf, xsq, idx, pn, pself, pcoup);
  nce_reduce<<<NR2 / 256, b256, 0, stream>>>(pn, pself, pcoup, part);

  finalize<<<1, 64, 0, stream>>>(part, out);
}